// Round 1
// baseline (99.785 us; speedup 1.0000x reference)
//
#include <hip/hip_runtime.h>

#define EPS_BN 1e-5f

// B=64, N=1024, C=32, O=64, K=16. kNN/gather in the reference is dead code
// (neigh == x for all k) so mean over k is identity:
// out[b,o,n] = gelu(bn3(W3.gelu(bn2(W2.gelu(bn1(W1.x[b,n,:]))))))[o], all f32 I/O.
//
// R10 was 96.72us. Counters showed the timed region is ~84us of harness
// re-poison fills (2x 42us fillBufferAligned @80% HBM peak); mlp_fused itself
// is ~10-13us vs a ~4us HBM roofline (25MB traffic). Grid 1024 = exactly one
// occupancy round (4 blocks/CU), so per-block prologue latency is unhidden.
// R11: collapse the two prologue barriers into one — fold threads compute BN
// scales inline from g/v scalar loads hoisted to the top (L2-hit), so the
// bias phase (scb) and the weight fold are independent and share a single
// __syncthreads. Removes barrier #1 + the phaseA->fold serial dependency.

typedef __attribute__((ext_vector_type(8))) short short8;   // 8 bf16 = 4 VGPRs
typedef __attribute__((ext_vector_type(4))) float f32x4;

__device__ __forceinline__ unsigned short f2bf(float f) {   // RNE f32->bf16
    unsigned int u = __float_as_uint(f);
    u += 0x7fffu + ((u >> 16) & 1u);
    return (unsigned short)(u >> 16);
}

// tanh-approx gelu, branchless, HW exp2 + rcp (R5-validated).
__device__ __forceinline__ float gelu(float v) {
    float v2 = v * v;
    float inner = fmaf(0.044715f, v2, 1.0f);
    float m = (v * 2.3022082f) * inner;
    float z = __builtin_amdgcn_exp2f(m);
    float r = __builtin_amdgcn_rcpf(z + 1.0f);
    float t = fmaf(-2.0f, r, 1.0f);
    float h = 0.5f * v;
    return fmaf(h, t, h);
}

// Block = 256 threads = 4 waves; each wave owns one 16-point m-tile.
// Grid = 1024 blocks. LDS map (30464 B):
//   [0,20480)      wlds: bf16 weights, fragment order (A-operand after swap)
//     stage1 @0:    [t:4][lane:64][j:8]
//     stage2 @2048: [t:4][kk:2][lane:64][j:8]
//     stage3 @6144: same
//   [20480,29696)  actsb: 4 waves x 16x72 bf16 act tiles [point][o]
//   [29696,30464)  scb: 192 f32 folded BN biases (scales now inline per-thread)
// MFMA 16x16x32 maps (measured m89/m120): A[m=lane&15][k=q*8+j],
// B[k=q*8+j][n=lane&15], C/D: col=lane&15, row=q*4+reg.
__global__ __launch_bounds__(256, 4)
void mlp_fused(const float* __restrict__ x,
               const float* __restrict__ W1,
               const float* __restrict__ g1, const float* __restrict__ bb1,
               const float* __restrict__ m1, const float* __restrict__ v1,
               const float* __restrict__ W2,
               const float* __restrict__ g2, const float* __restrict__ bb2,
               const float* __restrict__ m2, const float* __restrict__ v2,
               const float* __restrict__ W3,
               const float* __restrict__ g3, const float* __restrict__ bb3,
               const float* __restrict__ m3, const float* __restrict__ v3,
               float* __restrict__ out)
{
    __shared__ uint4 smem4[1904];                                   // 30464 B
    unsigned short* wlds = (unsigned short*)smem4;                  // 20480 B
    unsigned short* actsb = (unsigned short*)((char*)smem4 + 20480);
    float* scb = (float*)((char*)smem4 + 29696);   // 192 f32 folded biases

    const int tid = threadIdx.x;
    const int wave = tid >> 6, lane = tid & 63;
    const int q = lane >> 4, l15 = lane & 15;

    const int p0 = (blockIdx.x * 4 + wave) * 16;

    // ---- x prefetch (B-frag: point=lane&15, c-chunk=q*8..q*8+7) ----
    const float4* xp = (const float4*)(x + (size_t)(p0 + l15) * 32 + q * 8);
    float4 xa = xp[0], xb = xp[1];

    // ---- inline-scale g/v prefetch (L2-hit scalars; overlap weight loads) ----
    const int o1 = tid >> 3;          // W1 fold o (r=0; r=1 adds +32)
    const int o2 = tid >> 4;          // W2/W3 fold o base (+16*r)
    float g1a = g1[o1],      v1a = v1[o1];
    float g1b = g1[o1 + 32], v1b = v1[o1 + 32];
    float g2r[4], v2r[4], g3r[4], v3r[4];
#pragma unroll
    for (int r = 0; r < 4; ++r) {
        g2r[r] = g2[o2 + 16 * r]; v2r[r] = v2[o2 + 16 * r];
        g3r[r] = g3[o2 + 16 * r]; v3r[r] = v3[o2 + 16 * r];
    }

    // ---- weight prefetch to registers (latency overlaps bias phase) ----
    float4 w1r[2], w2r[4], w3r[4];
#pragma unroll
    for (int r = 0; r < 2; ++r) w1r[r] = ((const float4*)W1)[tid + r * 256];
#pragma unroll
    for (int r = 0; r < 4; ++r) w2r[r] = ((const float4*)W2)[tid + r * 256];
#pragma unroll
    for (int r = 0; r < 4; ++r) w3r[r] = ((const float4*)W3)[tid + r * 256];

    // ---- bias phase: 192 folded BN bias terms (independent of fold below) ----
    if (tid < 192) {
        int s = tid >> 6, o = tid & 63;
        const float* gg  = (s == 0) ? g1  : (s == 1) ? g2  : g3;
        const float* vv  = (s == 0) ? v1  : (s == 1) ? v2  : v3;
        const float* bbp = (s == 0) ? bb1 : (s == 1) ? bb2 : bb3;
        const float* mm  = (s == 0) ? m1  : (s == 1) ? m2  : m3;
        float sc = gg[o] * rsqrtf(vv[o] + EPS_BN);
        scb[tid] = bbp[o] - mm[o] * sc;
    }

    // ---- weight fold: scale (inline) -> swizzled bf16 LDS ----
    // 4 fragment-order dests per source float4 are consecutive -> ds_write_b64.
#pragma unroll
    for (int r = 0; r < 2; ++r) {
        int e4 = tid + r * 256;
        float4 w = w1r[r];
        int s0 = e4 << 2;
        int o = s0 >> 5, c0 = s0 & 31;
        float sc = (r == 0) ? g1a * rsqrtf(v1a + EPS_BN)
                            : g1b * rsqrtf(v1b + EPS_BN);
        int dst = ((o >> 4) << 9) + (((((c0 >> 3) << 4) | (o & 15))) << 3) + (c0 & 7);
        unsigned short pk[4] = { f2bf(w.x * sc), f2bf(w.y * sc),
                                 f2bf(w.z * sc), f2bf(w.w * sc) };
        *(uint2*)(wlds + dst) = *(const uint2*)pk;
    }
#pragma unroll
    for (int r = 0; r < 4; ++r) {
        int e4 = tid + r * 256;
        float4 w = w2r[r];
        int s0 = e4 << 2;
        int o = s0 >> 6, c0 = s0 & 63;
        float sc = g2r[r] * rsqrtf(v2r[r] + EPS_BN);
        int dst = 2048 + ((o >> 4) << 10) + ((c0 >> 5) << 9)
                + ((((((c0 >> 3) & 3) << 4) | (o & 15))) << 3) + (c0 & 7);
        unsigned short pk[4] = { f2bf(w.x * sc), f2bf(w.y * sc),
                                 f2bf(w.z * sc), f2bf(w.w * sc) };
        *(uint2*)(wlds + dst) = *(const uint2*)pk;
    }
#pragma unroll
    for (int r = 0; r < 4; ++r) {
        int e4 = tid + r * 256;
        float4 w = w3r[r];
        int s0 = e4 << 2;
        int o = s0 >> 6, c0 = s0 & 63;
        float sc = g3r[r] * rsqrtf(v3r[r] + EPS_BN);
        int dst = 6144 + ((o >> 4) << 10) + ((c0 >> 5) << 9)
                + ((((((c0 >> 3) & 3) << 4) | (o & 15))) << 3) + (c0 & 7);
        unsigned short pk[4] = { f2bf(w.x * sc), f2bf(w.y * sc),
                                 f2bf(w.z * sc), f2bf(w.w * sc) };
        *(uint2*)(wlds + dst) = *(const uint2*)pk;
    }
    __syncthreads();   // single barrier: biases + folded weights staged

    // ---- stage-1 B-frag (acts side) from prefetched x ----
    short8 a1;
    a1[0] = (short)f2bf(xa.x); a1[1] = (short)f2bf(xa.y);
    a1[2] = (short)f2bf(xa.z); a1[3] = (short)f2bf(xa.w);
    a1[4] = (short)f2bf(xb.x); a1[5] = (short)f2bf(xb.y);
    a1[6] = (short)f2bf(xb.z); a1[7] = (short)f2bf(xb.w);

    unsigned short* aw = actsb + wave * (16 * 72);

    // ---- stage 1: 32 -> 64.  D[row=o=q*4+r][col=point=l15] ----
#pragma unroll
    for (int t = 0; t < 4; ++t) {
        f32x4 acc = *(const f32x4*)(scb + 0 * 64 + t * 16 + q * 4);  // broadcast
        short8 wf = *(const short8*)(wlds + ((t * 64 + lane) << 3));
        acc = __builtin_amdgcn_mfma_f32_16x16x32_bf16(wf, a1, acc, 0, 0, 0);
        unsigned short pk[4] = { f2bf(gelu(acc[0])), f2bf(gelu(acc[1])),
                                 f2bf(gelu(acc[2])), f2bf(gelu(acc[3])) };
        *(uint2*)(aw + l15 * 72 + t * 16 + q * 4) = *(const uint2*)pk;  // [point][o]
    }
    __threadfence_block();

    // ---- stage 2: 64 -> 64 ----
    short8 a20 = *(const short8*)(aw + l15 * 72 + q * 8);        // acts[point][c0..]
    short8 a21 = *(const short8*)(aw + l15 * 72 + 32 + q * 8);
#pragma unroll
    for (int t = 0; t < 4; ++t) {
        f32x4 acc = *(const f32x4*)(scb + 1 * 64 + t * 16 + q * 4);
        short8 w0 = *(const short8*)(wlds + 2048 + ((t * 2 + 0) * 64 + lane) * 8);
        short8 w1 = *(const short8*)(wlds + 2048 + ((t * 2 + 1) * 64 + lane) * 8);
        acc = __builtin_amdgcn_mfma_f32_16x16x32_bf16(w0, a20, acc, 0, 0, 0);
        acc = __builtin_amdgcn_mfma_f32_16x16x32_bf16(w1, a21, acc, 0, 0, 0);
        unsigned short pk[4] = { f2bf(gelu(acc[0])), f2bf(gelu(acc[1])),
                                 f2bf(gelu(acc[2])), f2bf(gelu(acc[3])) };
        *(uint2*)(aw + l15 * 72 + t * 16 + q * 4) = *(const uint2*)pk;
    }
    __threadfence_block();

    // ---- stage 3: 64 -> 64, direct stores (quad = 64B run of out[o][n]) ----
    short8 a30 = *(const short8*)(aw + l15 * 72 + q * 8);
    short8 a31 = *(const short8*)(aw + l15 * 72 + 32 + q * 8);
    const int bb = p0 >> 10;
    const int n0 = p0 & 1023;
    float* outb = out + (size_t)bb * 65536 + n0 + l15;
#pragma unroll
    for (int t = 0; t < 4; ++t) {
        f32x4 acc = *(const f32x4*)(scb + 2 * 64 + t * 16 + q * 4);
        short8 w0 = *(const short8*)(wlds + 6144 + ((t * 2 + 0) * 64 + lane) * 8);
        short8 w1 = *(const short8*)(wlds + 6144 + ((t * 2 + 1) * 64 + lane) * 8);
        acc = __builtin_amdgcn_mfma_f32_16x16x32_bf16(w0, a30, acc, 0, 0, 0);
        acc = __builtin_amdgcn_mfma_f32_16x16x32_bf16(w1, a31, acc, 0, 0, 0);
#pragma unroll
        for (int r = 0; r < 4; ++r)
            outb[(size_t)(t * 16 + q * 4 + r) * 1024] = gelu(acc[r]);
    }
}

extern "C" void kernel_launch(void* const* d_in, const int* in_sizes, int n_in,
                              void* d_out, int out_size, void* d_ws, size_t ws_size,
                              hipStream_t stream) {
    const float* x  = (const float*)d_in[0];
    const float* W1 = (const float*)d_in[1];
    const float* g1 = (const float*)d_in[2];
    const float* b1 = (const float*)d_in[3];
    const float* m1 = (const float*)d_in[4];
    const float* v1 = (const float*)d_in[5];
    const float* W2 = (const float*)d_in[6];
    const float* g2 = (const float*)d_in[7];
    const float* b2 = (const float*)d_in[8];
    const float* m2 = (const float*)d_in[9];
    const float* v2 = (const float*)d_in[10];
    const float* W3 = (const float*)d_in[11];
    const float* g3 = (const float*)d_in[12];
    const float* b3 = (const float*)d_in[13];
    const float* m3 = (const float*)d_in[14];
    const float* v3 = (const float*)d_in[15];
    float* out = (float*)d_out;

    mlp_fused<<<1024, 256, 0, stream>>>(x, W1, g1, b1, m1, v1,
                                        W2, g2, b2, m2, v2,
                                        W3, g3, b3, m3, v3, out);
}